// Round 3
// baseline (153.596 us; speedup 1.0000x reference)
//
#include <hip/hip_runtime.h>
#include <hip/hip_bf16.h>

// Problem constants (fixed by the reference setup)
constexpr int   kB    = 2048;    // rows in feats
constexpr int   kC    = 256;     // feature dim
constexpr int   kG    = 128;     // group size = topk * num_instances
constexpr int   kKg   = 128;     // number of label groups
constexpr float kTemp = 0.05f;
constexpr float kEps  = 1e-6f;

typedef short bf16x8 __attribute__((ext_vector_type(8)));   // 8 bf16 in 4 VGPRs
typedef float floatx4 __attribute__((ext_vector_type(4)));  // MFMA accumulator

__device__ __forceinline__ unsigned short bf16_rne(float x) {
    union { float f; unsigned int u; } c; c.f = x;
    unsigned int r = c.u + 0x7FFFu + ((c.u >> 16) & 1u);  // round-to-nearest-even
    return (unsigned short)(r >> 16);
}

// Kernel 1: for each (64-row tile, group) block, compute the 64x128 tile of
// dot(feats, Fs^T), reduce min & max over the 128 group columns per row, and
// emit exp(min/T) to pos_e (if own-label group) else atomicAdd exp(max/T)
// into neg_e.  exp is monotone, so exp(min(dot))/exp(max(dot)) == min/max of
// exp(dot) — we never materialize the [2048,16384] matrix.
// Inputs are fp32 (per reference dtype); converted to bf16 during LDS staging
// for MFMA. R2 post-mortem: reading fp32 as bf16 produced NaNs.
__global__ __launch_bounds__(256, 4) void sim_minmax_kernel(
    const float* __restrict__ feats,    // [2048, 256] fp32
    const float* __restrict__ feats_s,  // [16384, 256] fp32 (flattened)
    const int* __restrict__ labels,     // [2048]
    const int* __restrict__ labels_s,   // [16384]
    float* __restrict__ pos_e,          // [2048]
    float* __restrict__ neg_e)          // [2048]
{
    const int group = blockIdx.x;       // 0..127
    const int row0  = blockIdx.y * 64;  // 0..2047 step 64
    const int n0    = group * kG;       // base row in Fs / labels_s

    // +8 element pad (16B) keeps 8/16B alignment and spreads banks
    __shared__ __hip_bfloat16 As[64][72];
    __shared__ __hip_bfloat16 Bs[128][72];
    __shared__ float rmin[64][4];
    __shared__ float rmax[64][4];

    const int t    = threadIdx.x;
    const int wave = t >> 6;
    const int lane = t & 63;
    const int l15  = lane & 15;
    const int quad = lane >> 4;

    floatx4 acc[4][2];
#pragma unroll
    for (int mt = 0; mt < 4; mt++)
#pragma unroll
        for (int nt = 0; nt < 2; nt++)
            acc[mt][nt] = (floatx4){0.f, 0.f, 0.f, 0.f};

    // K loop: 4 chunks of BK=64
    for (int k0 = 0; k0 < kC; k0 += 64) {
        // Stage A: 64 rows x 64 cols fp32 -> bf16. 16 threads/row, 4 floats
        // (float4) per thread, packed to ushort4 (8B) LDS write. 4 passes.
#pragma unroll
        for (int rep = 0; rep < 4; rep++) {
            int i = t + rep * 256;
            int r = i >> 4;
            int c = (i & 15) * 4;
            float4 v = *(const float4*)(feats + (size_t)(row0 + r) * kC + k0 + c);
            ushort4 p;
            p.x = bf16_rne(v.x); p.y = bf16_rne(v.y);
            p.z = bf16_rne(v.z); p.w = bf16_rne(v.w);
            *(ushort4*)(&As[r][c]) = p;
        }
        // Stage B: 128 rows x 64 cols fp32 -> bf16. 8 passes.
#pragma unroll
        for (int rep = 0; rep < 8; rep++) {
            int i = t + rep * 256;
            int r = i >> 4;
            int c = (i & 15) * 4;
            float4 v = *(const float4*)(feats_s + (size_t)(n0 + r) * kC + k0 + c);
            ushort4 p;
            p.x = bf16_rne(v.x); p.y = bf16_rne(v.y);
            p.z = bf16_rne(v.z); p.w = bf16_rne(v.w);
            *(ushort4*)(&Bs[r][c]) = p;
        }
        __syncthreads();

#pragma unroll
        for (int kk = 0; kk < 64; kk += 32) {
            bf16x8 a[4], b[2];
#pragma unroll
            for (int mt = 0; mt < 4; mt++)
                a[mt] = *(const bf16x8*)(&As[mt * 16 + l15][kk + quad * 8]);
#pragma unroll
            for (int nt = 0; nt < 2; nt++)
                b[nt] = *(const bf16x8*)(&Bs[wave * 32 + nt * 16 + l15][kk + quad * 8]);
#pragma unroll
            for (int mt = 0; mt < 4; mt++)
#pragma unroll
                for (int nt = 0; nt < 2; nt++)
                    acc[mt][nt] = __builtin_amdgcn_mfma_f32_16x16x32_bf16(
                        a[mt], b[nt], acc[mt][nt], 0, 0, 0);
        }
        __syncthreads();
    }

    // Reduce min/max over this wave's 32 columns, per row.
    // D layout: col = lane&15 (n), row = quad*4 + reg (m within 16x16 tile).
#pragma unroll
    for (int mt = 0; mt < 4; mt++) {
#pragma unroll
        for (int reg = 0; reg < 4; reg++) {
            float vn = fminf(acc[mt][0][reg], acc[mt][1][reg]);
            float vx = fmaxf(acc[mt][0][reg], acc[mt][1][reg]);
            // reduce across the 16 lanes (columns) of this quad
#pragma unroll
            for (int s = 1; s < 16; s <<= 1) {
                vn = fminf(vn, __shfl_xor(vn, s, 64));
                vx = fmaxf(vx, __shfl_xor(vx, s, 64));
            }
            if (l15 == 0) {
                int r = mt * 16 + quad * 4 + reg;
                rmin[r][wave] = vn;
                rmax[r][wave] = vx;
            }
        }
    }
    __syncthreads();

    if (t < 64) {
        float mn = fminf(fminf(rmin[t][0], rmin[t][1]), fminf(rmin[t][2], rmin[t][3]));
        float mx = fmaxf(fmaxf(rmax[t][0], rmax[t][1]), fmaxf(rmax[t][2], rmax[t][3]));
        int gb = row0 + t;
        const float invT = 1.0f / kTemp;
        if (labels[gb] == labels_s[n0]) {
            pos_e[gb] = expf(mn * invT);          // unique writer per row
        } else {
            atomicAdd(&neg_e[gb], expf(mx * invT));
        }
    }
}

// Kernel 2: per-row loss + mean over 2048 rows -> single fp32 scalar.
__global__ void finalize_kernel(const float* __restrict__ pos_e,
                                const float* __restrict__ neg_e,
                                float* __restrict__ out)
{
    __shared__ float red[256];
    float s = 0.f;
    for (int r = threadIdx.x; r < kB; r += 256) {
        float p = pos_e[r];
        float n = neg_e[r];
        s += -logf(p / (p + n + kEps) + kEps);
    }
    red[threadIdx.x] = s;
    __syncthreads();
    for (int off = 128; off > 0; off >>= 1) {
        if (threadIdx.x < off) red[threadIdx.x] += red[threadIdx.x + off];
        __syncthreads();
    }
    if (threadIdx.x == 0) out[0] = red[0] / (float)kB;
}

extern "C" void kernel_launch(void* const* d_in, const int* in_sizes, int n_in,
                              void* d_out, int out_size, void* d_ws, size_t ws_size,
                              hipStream_t stream) {
    (void)in_sizes; (void)n_in; (void)out_size; (void)ws_size;

    const float* feats    = (const float*)d_in[0];
    const float* feats_s  = (const float*)d_in[1];
    const int*   labels   = (const int*)d_in[2];
    const int*   labels_s = (const int*)d_in[3];
    // d_in[4] = topk (8), d_in[5] = num_instances (16) — fixed, hard-coded.

    float* pos_e = (float*)d_ws;          // [2048]
    float* neg_e = pos_e + kB;            // [2048]

    hipMemsetAsync(d_ws, 0, 2 * kB * sizeof(float), stream);

    dim3 grid(kKg, kB / 64);   // 128 groups x 32 row-tiles = 4096 blocks
    sim_minmax_kernel<<<grid, 256, 0, stream>>>(feats, feats_s, labels, labels_s,
                                                pos_e, neg_e);
    finalize_kernel<<<1, 256, 0, stream>>>(pos_e, neg_e, (float*)d_out);
}